// Round 5
// baseline (156.999 us; speedup 1.0000x reference)
//
#include <hip/hip_runtime.h>

// StructureTensorEffect: B=4, C=3, H=W=1024, fp32.
// Round 5: R3 structure (1 col/thread, ROWS=4 vertical streaming, lean
// constant-index accumulate) pushed across the VGPR occupancy tier:
// __launch_bounds__(256,8) caps at 64 VGPR (R3 sat at 68 -> 50% tier lost).
// Occupancy evidence: R1 32VGPR/72%occ/60us, R3 68/25%/43.6, R4 152/7.3%/62.6
// -- this kernel is latency-bound; waves are the lever, not instructions.
// IP=0 trim: cp0 = min(x+0,1023) = x identically, so b0 == cc (4 loads/row).

#define W_ 1024
#define H_ 1024
#define PLANE (1 << 20)
#define ROWS 4

__device__ __forceinline__ float lerp1(float a, float b, float f) {
    return fmaf(f, b - a, a);
}

// Exact per-pixel reference path (any sigma, any border) — verified R1-R4.
__device__ void slow_pixel(const float* __restrict__ Xb, float* __restrict__ Ob,
                           float sg, int xi, int y)
{
    float imf = floorf(-sg), ipf = floorf(sg);
    float fm  = -sg - imf;
    float fp  =  sg - ipf;
    int   im  = (int)imf, ip = (int)ipf;

    int cm0 = min(max(xi + im, 0), W_ - 1), cm1 = min(cm0 + 1, W_ - 1);
    int cp0 = min(max(xi + ip, 0), W_ - 1), cp1 = min(cp0 + 1, W_ - 1);
    int rm0 = min(max(y + im, 0), H_ - 1),  rm1 = min(rm0 + 1, H_ - 1);
    int rp0 = min(max(y + ip, 0), H_ - 1),  rp1 = min(rp0 + 1, H_ - 1);

    int o_rm0 = rm0 << 10, o_rm1 = rm1 << 10;
    int o_rp0 = rp0 << 10, o_rp1 = rp1 << 10;
    int o_r0  = y   << 10;

    float oxx = 0.f, oyy = 0.f, oxy = 0.f;

    #pragma unroll
    for (int c = 0; c < 3; ++c) {
        const float* base = Xb + ((size_t)c << 20);

        float hm_m0 = lerp1(base[o_rm0 + cm0], base[o_rm0 + cm1], fm);
        float hm_m1 = lerp1(base[o_rm1 + cm0], base[o_rm1 + cm1], fm);
        float hm_0  = lerp1(base[o_r0  + cm0], base[o_r0  + cm1], fm);
        float hm_p0 = lerp1(base[o_rp0 + cm0], base[o_rp0 + cm1], fm);
        float hm_p1 = lerp1(base[o_rp1 + cm0], base[o_rp1 + cm1], fm);
        float hp_m0 = lerp1(base[o_rm0 + cp0], base[o_rm0 + cp1], fp);
        float hp_m1 = lerp1(base[o_rm1 + cp0], base[o_rm1 + cp1], fp);
        float hp_0  = lerp1(base[o_r0  + cp0], base[o_r0  + cp1], fp);
        float hp_p0 = lerp1(base[o_rp0 + cp0], base[o_rp0 + cp1], fp);
        float hp_p1 = lerp1(base[o_rp1 + cp0], base[o_rp1 + cp1], fp);
        float h0_m0 = base[o_rm0 + xi], h0_m1 = base[o_rm1 + xi];
        float h0_p0 = base[o_rp0 + xi], h0_p1 = base[o_rp1 + xi];

        float t0 = lerp1(hm_m0, hm_m1, fm);
        float t1 = hm_0;
        float t2 = lerp1(hm_p0, hm_p1, fp);
        float t3 = lerp1(h0_m0, h0_m1, fm);
        float t4 = lerp1(h0_p0, h0_p1, fp);
        float t5 = lerp1(hp_m0, hp_m1, fm);
        float t6 = hp_0;
        float t7 = lerp1(hp_p0, hp_p1, fp);

        float su = 0.25f * (t5 + t7 - t0 - t2) + 0.5f * (t6 - t1);
        float sv = 0.25f * (t2 + t7 - t0 - t5) + 0.5f * (t4 - t3);

        float l2 = (c == 0) ? 10000.f : 1.f;
        oxx = fmaf(l2 * su, su, oxx);
        oyy = fmaf(l2 * sv, sv, oyy);
        oxy = fmaf(l2 * su, sv, oxy);
    }

    int pix = (y << 10) | xi;
    Ob[pix]             = oxx;
    Ob[PLANE + pix]     = oyy;
    Ob[2 * PLANE + pix] = oxy;
}

template<int N>
__device__ __forceinline__ void acc(float (&arr)[N], int k, float val) {
    if (k >= 0 && k < N) arr[k] += val;   // k is constant after unroll
}

// Fast path: im = -(IP+1), ip = IP, fm = 1-fp, all rows interior.
// Thread owns column x, rows y0..y0+ROWS-1. Shared-row streaming:
// per row w compute A=0.25*(hp-hm), hq=0.5*(hp-hm), B=0.25*(hm+hp)+0.5*cc,
// scatter into su/sv at constant indices.
template<int IP>
__device__ void fast4(const float* __restrict__ Xb, float* __restrict__ Ob,
                      float fp, float fm, int x, int y0)
{
    constexpr int RW = ROWS + 2 * IP + 2;   // shared rows y0-IP-1 .. y0+ROWS+IP

    int cm0 = max(x - (IP + 1), 0);
    int cm1 = cm0 + 1;                      // cm0 <= 1022 always
    int cp0 = min(x + IP, W_ - 1);
    int cp1 = min(cp0 + 1, W_ - 1);

    float oxx[ROWS], oyy[ROWS], oxy[ROWS];
    #pragma unroll
    for (int k = 0; k < ROWS; ++k) { oxx[k] = 0.f; oyy[k] = 0.f; oxy[k] = 0.f; }

    #pragma unroll
    for (int c = 0; c < 3; ++c) {
        const float* base = Xb + ((size_t)c << 20) + ((y0 - IP - 1) << 10);
        float su[ROWS], sv[ROWS];
        #pragma unroll
        for (int k = 0; k < ROWS; ++k) { su[k] = 0.f; sv[k] = 0.f; }

        #pragma unroll
        for (int w = 0; w < RW; ++w) {
            const float* rp = base + (w << 10);
            float a0 = rp[cm0], a1 = rp[cm1];
            float cc = rp[x];
            // IP==0: cp0 = min(x,1023) = x identically -> b0 == cc.
            float b0 = (IP == 0) ? cc : rp[cp0];
            float b1 = rp[cp1];
            float hm = lerp1(a0, a1, fm);
            float hp = lerp1(b0, b1, fp);
            float q  = hp - hm;
            float A  = 0.25f * q;
            float hq = 0.5f  * q;
            float Bv = fmaf(0.25f, hm + hp, 0.5f * cc);
            float fpA = fp * A, fmA = fm * A;
            float fpB = fp * Bv, fmB = fm * Bv;

            acc(su, w,              fpA);
            acc(su, w - 1,          fmA);
            acc(su, w - IP - 1,     hq);
            acc(su, w - 2*IP - 1,   fmA);
            acc(su, w - 2*IP - 2,   fpA);
            acc(sv, w,             -fpB);
            acc(sv, w - 1,         -fmB);
            acc(sv, w - 2*IP - 1,   fmB);
            acc(sv, w - 2*IP - 2,   fpB);
        }

        float l2 = (c == 0) ? 10000.f : 1.f;
        #pragma unroll
        for (int k = 0; k < ROWS; ++k) {
            oxx[k] = fmaf(l2 * su[k], su[k], oxx[k]);
            oyy[k] = fmaf(l2 * sv[k], sv[k], oyy[k]);
            oxy[k] = fmaf(l2 * su[k], sv[k], oxy[k]);
        }
    }

    #pragma unroll
    for (int k = 0; k < ROWS; ++k) {
        int pix = ((y0 + k) << 10) | x;
        Ob[pix]             = oxx[k];
        Ob[PLANE + pix]     = oyy[k];
        Ob[2 * PLANE + pix] = oxy[k];
    }
}

// block = (64,4): 64 columns x 4 thread-rows, each thread ROWS=4 rows
// -> 64x16 pixel tile. Wave (64 lanes) = one thread-row: fast/slow branch
// is wave-uniform, loads 64-lane coalesced.
// __launch_bounds__(256,8): force <=64 VGPR -> 32-waves/CU occupancy tier.
__global__ __launch_bounds__(256, 8) void st_kernel(
    const float* __restrict__ X, const float* __restrict__ S,
    float* __restrict__ O)
{
    int x  = blockIdx.x * 64 + threadIdx.x;
    int y0 = blockIdx.y * 16 + threadIdx.y * ROWS;
    int b  = blockIdx.z;

    const float* Xb = X + (size_t)b * 3 * PLANE;
    float*       Ob = O + (size_t)b * 3 * PLANE;
    float sg = S[b];

    int ip = (int)floorf(sg);
    int im = (int)floorf(-sg);
    bool sig_ok = (im == -ip - 1) && ip >= 0 && ip <= 2;
    bool fast   = sig_ok && (y0 - ip - 1 >= 0) && (y0 + ROWS + ip <= H_ - 1);

    float fp = sg - (float)ip;
    float fm = 1.0f - fp;

    if (fast) {
        switch (ip) {
            case 0:  fast4<0>(Xb, Ob, fp, fm, x, y0); break;
            case 1:  fast4<1>(Xb, Ob, fp, fm, x, y0); break;
            default: fast4<2>(Xb, Ob, fp, fm, x, y0); break;
        }
    } else {
        for (int k = 0; k < ROWS; ++k)
            slow_pixel(Xb, Ob, sg, x, y0 + k);
    }
}

extern "C" void kernel_launch(void* const* d_in, const int* in_sizes, int n_in,
                              void* d_out, int out_size, void* d_ws, size_t ws_size,
                              hipStream_t stream) {
    const float* x     = (const float*)d_in[0];
    const float* sigma = (const float*)d_in[1];
    float* out = (float*)d_out;

    dim3 grid(W_ / 64, H_ / 16, 4), block(64, 4);
    hipLaunchKernelGGL(st_kernel, grid, block, 0, stream, x, sigma, out);
}

// Round 6
// 146.412 us; speedup vs baseline: 1.0723x; 1.0723x over previous
//
#include <hip/hip_runtime.h>

// StructureTensorEffect: B=4, C=3, H=W=1024, fp32.
// Round 6: 4 cols x 2 rows per thread; per shared row THREE aligned float4
// loads (cols x0-4..x0+7, clamped aligned group bases) serve all 4 columns'
// windows for IP<=2 -> wave-VMEM ~4x down vs R3 (the dominant reducible
// pipe). No rown/goff arrays (interior fast path = constant stride),
// channel-sequential su/sv keeps live regs ~70 (R4 spilled at 152; R5
// showed capping forces spills -> no min-waves cap here).
// Top/bottom rows: exact slow fallback per thread-row (wave-uniform).
// x-edge px (x<=IP, x>=1023-IP): store-masked, covered by border slice.

#define W_ 1024
#define H_ 1024
#define PLANE (1 << 20)

__device__ __forceinline__ float lerp1(float a, float b, float f) {
    return fmaf(f, b - a, a);
}

// Exact per-pixel reference path (any sigma, any border) — verified R1-R5.
__device__ void slow_pixel(const float* __restrict__ Xb, float* __restrict__ Ob,
                           float sg, int xi, int y)
{
    float imf = floorf(-sg), ipf = floorf(sg);
    float fm  = -sg - imf;
    float fp  =  sg - ipf;
    int   im  = (int)imf, ip = (int)ipf;

    int cm0 = min(max(xi + im, 0), W_ - 1), cm1 = min(cm0 + 1, W_ - 1);
    int cp0 = min(max(xi + ip, 0), W_ - 1), cp1 = min(cp0 + 1, W_ - 1);
    int rm0 = min(max(y + im, 0), H_ - 1),  rm1 = min(rm0 + 1, H_ - 1);
    int rp0 = min(max(y + ip, 0), H_ - 1),  rp1 = min(rp0 + 1, H_ - 1);

    int o_rm0 = rm0 << 10, o_rm1 = rm1 << 10;
    int o_rp0 = rp0 << 10, o_rp1 = rp1 << 10;
    int o_r0  = y   << 10;

    float oxx = 0.f, oyy = 0.f, oxy = 0.f;

    #pragma unroll
    for (int c = 0; c < 3; ++c) {
        const float* base = Xb + ((size_t)c << 20);

        float hm_m0 = lerp1(base[o_rm0 + cm0], base[o_rm0 + cm1], fm);
        float hm_m1 = lerp1(base[o_rm1 + cm0], base[o_rm1 + cm1], fm);
        float hm_0  = lerp1(base[o_r0  + cm0], base[o_r0  + cm1], fm);
        float hm_p0 = lerp1(base[o_rp0 + cm0], base[o_rp0 + cm1], fm);
        float hm_p1 = lerp1(base[o_rp1 + cm0], base[o_rp1 + cm1], fm);
        float hp_m0 = lerp1(base[o_rm0 + cp0], base[o_rm0 + cp1], fp);
        float hp_m1 = lerp1(base[o_rm1 + cp0], base[o_rm1 + cp1], fp);
        float hp_0  = lerp1(base[o_r0  + cp0], base[o_r0  + cp1], fp);
        float hp_p0 = lerp1(base[o_rp0 + cp0], base[o_rp0 + cp1], fp);
        float hp_p1 = lerp1(base[o_rp1 + cp0], base[o_rp1 + cp1], fp);
        float h0_m0 = base[o_rm0 + xi], h0_m1 = base[o_rm1 + xi];
        float h0_p0 = base[o_rp0 + xi], h0_p1 = base[o_rp1 + xi];

        float t0 = lerp1(hm_m0, hm_m1, fm);
        float t1 = hm_0;
        float t2 = lerp1(hm_p0, hm_p1, fp);
        float t3 = lerp1(h0_m0, h0_m1, fm);
        float t4 = lerp1(h0_p0, h0_p1, fp);
        float t5 = lerp1(hp_m0, hp_m1, fm);
        float t6 = hp_0;
        float t7 = lerp1(hp_p0, hp_p1, fp);

        float su = 0.25f * (t5 + t7 - t0 - t2) + 0.5f * (t6 - t1);
        float sv = 0.25f * (t2 + t7 - t0 - t5) + 0.5f * (t4 - t3);

        float l2 = (c == 0) ? 10000.f : 1.f;
        oxx = fmaf(l2 * su, su, oxx);
        oyy = fmaf(l2 * sv, sv, oyy);
        oxy = fmaf(l2 * su, sv, oxy);
    }

    int pix = (y << 10) | xi;
    Ob[pix]             = oxx;
    Ob[PLANE + pix]     = oyy;
    Ob[2 * PLANE + pix] = oxy;
}

template<int N>
__device__ __forceinline__ void acc(float (&arr)[N], int k, float val) {
    if (k >= 0 && k < N) arr[k] += val;   // k constant after unroll
}

// Fast path: thread = cols x0..x0+3 (x0 % 4 == 0), rows y0, y0+1.
// Rows guaranteed interior (caller checks). Window cols x0-4..x0+7 via
// three aligned float4 loads; group bases clamped (x0=0 duplicates low
// group, x0=1020 duplicates high group) — wrong only for px x<=IP or
// x>=W-1-IP, which are store-masked (border slice writes them).
// wv index of image col c is (c-x0)+4: a0=j+3-IP, a1=+1, cc=j+4,
// b0=j+4+IP, b1=+1 (j = col within thread, 0..3).
template<int IP>
__device__ void fast42(const float* __restrict__ Xb, float* __restrict__ Ob,
                       float fp, float fm, int x0, int y0)
{
    constexpr int RW = 2 + 2 * IP + 2;  // shared rows y0-IP-1 .. y0+2+IP
    constexpr int EA = 3 - IP;          // hm tap base wv-index (+j)
    constexpr int EB = 4 + IP;          // hp tap base wv-index (+j)

    int g0 = max(x0 - 4, 0);            // aligned, clamped group bases
    int g1 = x0;
    int g2 = min(x0 + 4, W_ - 4);

    float oxx[4][2], oyy[4][2], oxy[4][2];
    #pragma unroll
    for (int j = 0; j < 4; ++j)
        #pragma unroll
        for (int k = 0; k < 2; ++k) {
            oxx[j][k] = 0.f; oyy[j][k] = 0.f; oxy[j][k] = 0.f;
        }

    #pragma unroll
    for (int c = 0; c < 3; ++c) {
        const float* rowp = Xb + ((size_t)c << 20) + ((y0 - IP - 1) << 10);
        float su[4][2], sv[4][2];
        #pragma unroll
        for (int j = 0; j < 4; ++j) {
            su[j][0] = 0.f; su[j][1] = 0.f;
            sv[j][0] = 0.f; sv[j][1] = 0.f;
        }

        #pragma unroll
        for (int w = 0; w < RW; ++w) {
            const float* rp = rowp + (w << 10);
            float4 A4 = *reinterpret_cast<const float4*>(rp + g0);
            float4 B4 = *reinterpret_cast<const float4*>(rp + g1);
            float4 C4 = *reinterpret_cast<const float4*>(rp + g2);
            float wv[12] = {A4.x, A4.y, A4.z, A4.w,
                            B4.x, B4.y, B4.z, B4.w,
                            C4.x, C4.y, C4.z, C4.w};

            #pragma unroll
            for (int j = 0; j < 4; ++j) {
                float hm = lerp1(wv[j + EA], wv[j + EA + 1], fm);
                float hp = lerp1(wv[j + EB], wv[j + EB + 1], fp);
                float cc = wv[j + 4];
                float q  = hp - hm;
                float A  = 0.25f * q;
                float hq = 0.5f  * q;
                float Bv = fmaf(0.25f, hm + hp, 0.5f * cc);
                float fpA = fp * A,  fmA = fm * A;
                float fpB = fp * Bv, fmB = fm * Bv;

                acc(su[j], w,              fpA);
                acc(su[j], w - 1,          fmA);
                acc(su[j], w - IP - 1,     hq);
                acc(su[j], w - 2*IP - 1,   fmA);
                acc(su[j], w - 2*IP - 2,   fpA);
                acc(sv[j], w,             -fpB);
                acc(sv[j], w - 1,         -fmB);
                acc(sv[j], w - 2*IP - 1,   fmB);
                acc(sv[j], w - 2*IP - 2,   fpB);
            }
        }

        float l2 = (c == 0) ? 10000.f : 1.f;
        #pragma unroll
        for (int j = 0; j < 4; ++j)
            #pragma unroll
            for (int k = 0; k < 2; ++k) {
                oxx[j][k] = fmaf(l2 * su[j][k], su[j][k], oxx[j][k]);
                oyy[j][k] = fmaf(l2 * sv[j][k], sv[j][k], oyy[j][k]);
                oxy[j][k] = fmaf(l2 * su[j][k], sv[j][k], oxy[j][k]);
            }
    }

    bool ok[4];
    #pragma unroll
    for (int j = 0; j < 4; ++j)
        ok[j] = (x0 + j > IP) && (x0 + j < W_ - 1 - IP);
    bool all4 = ok[0] && ok[1] && ok[2] && ok[3];

    #pragma unroll
    for (int k = 0; k < 2; ++k) {
        int pix = ((y0 + k) << 10) | x0;
        if (all4) {
            *reinterpret_cast<float4*>(Ob + pix) =
                make_float4(oxx[0][k], oxx[1][k], oxx[2][k], oxx[3][k]);
            *reinterpret_cast<float4*>(Ob + PLANE + pix) =
                make_float4(oyy[0][k], oyy[1][k], oyy[2][k], oyy[3][k]);
            *reinterpret_cast<float4*>(Ob + 2 * PLANE + pix) =
                make_float4(oxy[0][k], oxy[1][k], oxy[2][k], oxy[3][k]);
        } else {
            #pragma unroll
            for (int j = 0; j < 4; ++j) {
                if (ok[j]) {
                    Ob[pix + j]             = oxx[j][k];
                    Ob[PLANE + pix + j]     = oyy[j][k];
                    Ob[2 * PLANE + pix + j] = oxy[j][k];
                }
            }
        }
    }
}

// block (64,4): thread = 4 cols x 2 rows -> tile 256x8 per block.
// gridDim.y has one extra slice (index H_/8) for x-border pixels.
__global__ __launch_bounds__(256) void st_kernel(
    const float* __restrict__ X, const float* __restrict__ S,
    float* __restrict__ O)
{
    int b  = blockIdx.z;
    const float* Xb = X + (size_t)b * 3 * PLANE;
    float*       Ob = O + (size_t)b * 3 * PLANE;
    float sg = S[b];

    if (blockIdx.y == (H_ / 8)) {
        // x-border slice: cols {0,1,2,1021,1022,1023}, all rows.
        // 6144 px per batch over gridDim.x*256 = 1024 threads -> 6 iters.
        int tid = blockIdx.x * 256 + threadIdx.y * 64 + threadIdx.x;
        #pragma unroll
        for (int it = 0; it < 6; ++it) {
            int pidx = tid + it * 1024;
            if (pidx < 6144) {
                int yy = pidx / 6;
                int cc = pidx - yy * 6;
                int xx = (cc < 3) ? cc : (W_ - 6 + cc);
                slow_pixel(Xb, Ob, sg, xx, yy);
            }
        }
        return;
    }

    int x0 = (blockIdx.x * 64 + threadIdx.x) * 4;
    int y0 = blockIdx.y * 8 + threadIdx.y * 2;

    int ipv = (int)floorf(sg);
    int imv = (int)floorf(-sg);
    bool sig_ok = (imv == -ipv - 1) && ipv >= 0 && ipv <= 2;
    // rows used by fast path must be interior: y0-ip-1 >= 0, y0+1+ip+1 <= H-1
    bool rows_ok = (y0 >= ipv + 1) && (y0 <= H_ - 3 - ipv);
    float fp = sg - (float)ipv;
    float fm = 1.0f - fp;

    if (sig_ok && rows_ok) {
        switch (ipv) {
            case 0:  fast42<0>(Xb, Ob, fp, fm, x0, y0); break;
            case 1:  fast42<1>(Xb, Ob, fp, fm, x0, y0); break;
            default: fast42<2>(Xb, Ob, fp, fm, x0, y0); break;
        }
    } else {
        #pragma unroll
        for (int k = 0; k < 2; ++k)
            #pragma unroll
            for (int j = 0; j < 4; ++j)
                slow_pixel(Xb, Ob, sg, x0 + j, y0 + k);
    }
}

extern "C" void kernel_launch(void* const* d_in, const int* in_sizes, int n_in,
                              void* d_out, int out_size, void* d_ws, size_t ws_size,
                              hipStream_t stream) {
    const float* x     = (const float*)d_in[0];
    const float* sigma = (const float*)d_in[1];
    float* out = (float*)d_out;

    // grid: x = 1024/(64 thr * 4 cols) = 4, y = 1024/8 + border slice, z = B
    dim3 grid(4, H_ / 8 + 1, 4), block(64, 4);
    hipLaunchKernelGGL(st_kernel, grid, block, 0, stream, x, sigma, out);
}

// Round 7
// 117.649 us; speedup vs baseline: 1.3345x; 1.2445x over previous
//
#include <hip/hip_runtime.h>

// StructureTensorEffect: B=4, C=3, H=W=1024, fp32.
// Round 7: LDS-staged tile. R4/R6 proved register-window reuse explodes
// VGPR (132-152 -> 6-7% occ); R3 (68 VGPR, 43.6us) is latency-bound with
// VALU+VMEM+HBM ~ equal and summing. This round: block stages a 72-col x
// (34+2IP)-row clamped window into LDS per channel (coalesced float4,
// ~2.7 loads/thread), then R3's streaming accumulate reads LDS via
// immediate-offset ds_read2 (one base addr/thread). Register live state
// ~60 (window in LDS, not VGPRs). Global VMEM 30/px -> ~1.3/px.
// Borders: row-clamped staging is exact for bottom/right (weights
// collapse, fm+fp=1); top (y<=ip) + x-edges store-masked, covered by the
// R4-proven border slice (x in {0,1,2,1021,1022,1023} all y; y in {0,1,2}
// all x).

#define W_ 1024
#define H_ 1024
#define PLANE (1 << 20)
#define TCOLS 64
#define TROWS 32
#define ROWS 8
#define LSTRIDE 72     // staged cols: x0-4 .. x0+67

__device__ __forceinline__ float lerp1(float a, float b, float f) {
    return fmaf(f, b - a, a);
}

// Exact per-pixel reference path (any sigma, any border) — verified R1-R6.
__device__ void slow_pixel(const float* __restrict__ Xb, float* __restrict__ Ob,
                           float sg, int xi, int y)
{
    float imf = floorf(-sg), ipf = floorf(sg);
    float fm  = -sg - imf;
    float fp  =  sg - ipf;
    int   im  = (int)imf, ip = (int)ipf;

    int cm0 = min(max(xi + im, 0), W_ - 1), cm1 = min(cm0 + 1, W_ - 1);
    int cp0 = min(max(xi + ip, 0), W_ - 1), cp1 = min(cp0 + 1, W_ - 1);
    int rm0 = min(max(y + im, 0), H_ - 1),  rm1 = min(rm0 + 1, H_ - 1);
    int rp0 = min(max(y + ip, 0), H_ - 1),  rp1 = min(rp0 + 1, H_ - 1);

    int o_rm0 = rm0 << 10, o_rm1 = rm1 << 10;
    int o_rp0 = rp0 << 10, o_rp1 = rp1 << 10;
    int o_r0  = y   << 10;

    float oxx = 0.f, oyy = 0.f, oxy = 0.f;

    #pragma unroll
    for (int c = 0; c < 3; ++c) {
        const float* base = Xb + ((size_t)c << 20);

        float hm_m0 = lerp1(base[o_rm0 + cm0], base[o_rm0 + cm1], fm);
        float hm_m1 = lerp1(base[o_rm1 + cm0], base[o_rm1 + cm1], fm);
        float hm_0  = lerp1(base[o_r0  + cm0], base[o_r0  + cm1], fm);
        float hm_p0 = lerp1(base[o_rp0 + cm0], base[o_rp0 + cm1], fm);
        float hm_p1 = lerp1(base[o_rp1 + cm0], base[o_rp1 + cm1], fm);
        float hp_m0 = lerp1(base[o_rm0 + cp0], base[o_rm0 + cp1], fp);
        float hp_m1 = lerp1(base[o_rm1 + cp0], base[o_rm1 + cp1], fp);
        float hp_0  = lerp1(base[o_r0  + cp0], base[o_r0  + cp1], fp);
        float hp_p0 = lerp1(base[o_rp0 + cp0], base[o_rp0 + cp1], fp);
        float hp_p1 = lerp1(base[o_rp1 + cp0], base[o_rp1 + cp1], fp);
        float h0_m0 = base[o_rm0 + xi], h0_m1 = base[o_rm1 + xi];
        float h0_p0 = base[o_rp0 + xi], h0_p1 = base[o_rp1 + xi];

        float t0 = lerp1(hm_m0, hm_m1, fm);
        float t1 = hm_0;
        float t2 = lerp1(hm_p0, hm_p1, fp);
        float t3 = lerp1(h0_m0, h0_m1, fm);
        float t4 = lerp1(h0_p0, h0_p1, fp);
        float t5 = lerp1(hp_m0, hp_m1, fm);
        float t6 = hp_0;
        float t7 = lerp1(hp_p0, hp_p1, fp);

        float su = 0.25f * (t5 + t7 - t0 - t2) + 0.5f * (t6 - t1);
        float sv = 0.25f * (t2 + t7 - t0 - t5) + 0.5f * (t4 - t3);

        float l2 = (c == 0) ? 10000.f : 1.f;
        oxx = fmaf(l2 * su, su, oxx);
        oyy = fmaf(l2 * sv, sv, oyy);
        oxy = fmaf(l2 * su, sv, oxy);
    }

    int pix = (y << 10) | xi;
    Ob[pix]             = oxx;
    Ob[PLANE + pix]     = oyy;
    Ob[2 * PLANE + pix] = oxy;
}

template<int N>
__device__ __forceinline__ void acc(float (&arr)[N], int k, float val) {
    if (k >= 0 && k < N) arr[k] += val;   // k constant after unroll
}

// Fast tile: block covers cols x0..x0+63, rows y0..y0+31. Per channel:
// stage LDS window (rows y0-IP-1..y0+32+IP clamped; cols x0-4..x0+67,
// float4 groups clamped to [0,1020]), then each thread streams RW window
// rows from LDS for its column x0+tx and 8 output rows y0+ty*8...
// Store mask (x>IP && x<1023-IP && y>IP) excludes the clamp-wrong px.
template<int IP>
__device__ void fast_tile(const float* __restrict__ Xb, float* __restrict__ Ob,
                          float fp, float fm, int x0, int y0,
                          int tx, int ty, int tid, float* smem)
{
    constexpr int LROWS = TROWS + 2 * IP + 2;   // staged rows
    constexpr int RW    = ROWS + 2 * IP + 2;    // window rows per thread
    constexpr int NG    = LROWS * 18;           // float4 groups to stage

    int x = x0 + tx;
    int Y = y0 + ty * ROWS;

    float oxx[ROWS], oyy[ROWS], oxy[ROWS];
    #pragma unroll
    for (int k = 0; k < ROWS; ++k) { oxx[k] = 0.f; oyy[k] = 0.f; oxy[k] = 0.f; }

    // thread's LDS read base: window row w lives at LDS row ty*ROWS + w;
    // LDS col idx of global col g is g - (x0-4); a0 is at col x-IP-1.
    const float* sp = smem + (ty * ROWS) * LSTRIDE + tx + (3 - IP);

    for (int c = 0; c < 3; ++c) {
        const float* Xc = Xb + ((size_t)c << 20);

        // ---- stage window into LDS (coalesced float4) ----
        for (int g = tid; g < NG; g += 256) {
            int row = g / 18;
            int grp = g - row * 18;
            int gr  = min(max(y0 - IP - 1 + row, 0), H_ - 1);
            int gc  = min(max(x0 - 4 + grp * 4, 0), W_ - 4);
            *reinterpret_cast<float4*>(&smem[row * LSTRIDE + grp * 4]) =
                *reinterpret_cast<const float4*>(&Xc[(gr << 10) + gc]);
        }
        __syncthreads();

        // ---- streaming accumulate from LDS ----
        float su[ROWS], sv[ROWS];
        #pragma unroll
        for (int k = 0; k < ROWS; ++k) { su[k] = 0.f; sv[k] = 0.f; }

        #pragma unroll
        for (int w = 0; w < RW; ++w) {
            float a0 = sp[w * LSTRIDE];
            float a1 = sp[w * LSTRIDE + 1];
            float cc = sp[w * LSTRIDE + IP + 1];
            float b0 = sp[w * LSTRIDE + 2 * IP + 1];
            float b1 = sp[w * LSTRIDE + 2 * IP + 2];
            float hm = lerp1(a0, a1, fm);
            float hp = lerp1(b0, b1, fp);
            float q  = hp - hm;
            float A  = 0.25f * q;
            float hq = 0.5f  * q;
            float Bv = fmaf(0.25f, hm + hp, 0.5f * cc);
            float fpA = fp * A,  fmA = fm * A;
            float fpB = fp * Bv, fmB = fm * Bv;

            acc(su, w,              fpA);
            acc(su, w - 1,          fmA);
            acc(su, w - IP - 1,     hq);
            acc(su, w - 2*IP - 1,   fmA);
            acc(su, w - 2*IP - 2,   fpA);
            acc(sv, w,             -fpB);
            acc(sv, w - 1,         -fmB);
            acc(sv, w - 2*IP - 1,   fmB);
            acc(sv, w - 2*IP - 2,   fpB);
        }

        float l2 = (c == 0) ? 10000.f : 1.f;
        #pragma unroll
        for (int k = 0; k < ROWS; ++k) {
            oxx[k] = fmaf(l2 * su[k], su[k], oxx[k]);
            oyy[k] = fmaf(l2 * sv[k], sv[k], oyy[k]);
            oxy[k] = fmaf(l2 * su[k], sv[k], oxy[k]);
        }
        __syncthreads();   // before restaging next channel
    }

    bool okx = (x > IP) && (x < W_ - 1 - IP);
    #pragma unroll
    for (int k = 0; k < ROWS; ++k) {
        int y = Y + k;
        if (okx && y > IP) {
            int pix = (y << 10) | x;
            Ob[pix]             = oxx[k];
            Ob[PLANE + pix]     = oyy[k];
            Ob[2 * PLANE + pix] = oxy[k];
        }
    }
}

// block (64,4). grid.y = 32 tile bands + 1 border slice.
__global__ __launch_bounds__(256) void st_kernel(
    const float* __restrict__ X, const float* __restrict__ S,
    float* __restrict__ O)
{
    int b  = blockIdx.z;
    const float* Xb = X + (size_t)b * 3 * PLANE;
    float*       Ob = O + (size_t)b * 3 * PLANE;
    float sg = S[b];

    int tx = threadIdx.x, ty = threadIdx.y;
    int tid = ty * 64 + tx;

    if (blockIdx.y == (H_ / TROWS)) {
        // Border slice: x in {0,1,2,1021,1022,1023} all y (6144 px) plus
        // y in {0,1,2} all x (3072 px). 16*256 = 4096 threads -> 3 iters.
        int t = blockIdx.x * 256 + tid;
        #pragma unroll
        for (int it = 0; it < 3; ++it) {
            int pidx = t + it * 4096;
            if (pidx < 6144) {
                int yy = pidx / 6;
                int cc = pidx - yy * 6;
                int xx = (cc < 3) ? cc : (W_ - 6 + cc);
                slow_pixel(Xb, Ob, sg, xx, yy);
            } else if (pidx < 9216) {
                int p2 = pidx - 6144;
                slow_pixel(Xb, Ob, sg, p2 & 1023, p2 >> 10);
            }
        }
        return;
    }

    int x0 = blockIdx.x * TCOLS;
    int y0 = blockIdx.y * TROWS;

    int ipv = (int)floorf(sg);
    int imv = (int)floorf(-sg);
    bool sig_ok = (imv == -ipv - 1) && ipv >= 0 && ipv <= 2;  // block-uniform
    float fp = sg - (float)ipv;
    float fm = 1.0f - fp;

    __shared__ float smem[(TROWS + 6) * LSTRIDE];   // worst case IP=2: 38x72

    if (sig_ok) {
        switch (ipv) {
            case 0:  fast_tile<0>(Xb, Ob, fp, fm, x0, y0, tx, ty, tid, smem); break;
            case 1:  fast_tile<1>(Xb, Ob, fp, fm, x0, y0, tx, ty, tid, smem); break;
            default: fast_tile<2>(Xb, Ob, fp, fm, x0, y0, tx, ty, tid, smem); break;
        }
    } else {
        for (int k = 0; k < ROWS; ++k)
            slow_pixel(Xb, Ob, sg, x0 + tx, y0 + ty * ROWS + k);
    }
}

extern "C" void kernel_launch(void* const* d_in, const int* in_sizes, int n_in,
                              void* d_out, int out_size, void* d_ws, size_t ws_size,
                              hipStream_t stream) {
    const float* x     = (const float*)d_in[0];
    const float* sigma = (const float*)d_in[1];
    float* out = (float*)d_out;

    dim3 grid(W_ / TCOLS, H_ / TROWS + 1, 4), block(64, 4);
    hipLaunchKernelGGL(st_kernel, grid, block, 0, stream, x, sigma, out);
}